// Round 7
// baseline (1826.471 us; speedup 1.0000x reference)
//
#include <hip/hip_runtime.h>

#define HH 64
#define TT 2048
#define BB 256
#define YSZ (BB*TT)   // y elements before hT in d_out

__device__ __forceinline__ float sigmoid_f(float v) {
    return 1.0f / (1.0f + __expf(-v));
}
__device__ __forceinline__ float tanh_f(float v) {
    return 1.0f - 2.0f / (1.0f + __expf(2.0f * v));
}

// Rounds 1-5: hipcc's pressure heuristic refuses to keep >~30 invariant weight
// floats in VGPRs across the barrier loop (VGPR_Count 124/88/88/80/60), so
// weights were re-fetched from L1 every timestep (~1200 cyc/iter). Round 6:
// gfx950 rejects AGPR as a direct VALU source (v_fmac_f32 vD, aN, vS illegal),
// but v_accvgpr_read/write assemble fine. So: pin weights in AGPRs (unified
// file, no MFMA in this kernel -> class is empty) and do an explicit
// v_accvgpr_read before each FMA. 2 instr/MAC, but zero cache traffic and
// non-rematerializable by construction.
#define AW(dst, val)  asm("v_accvgpr_write_b32 %0, %1" : "=a"(dst) : "v"(val))
#define AR(dst, src)  asm("v_accvgpr_read_b32 %0, %1"  : "=v"(dst) : "a"(src))
#define AMAC(acc, w, h) { float _t_; AR(_t_, w); acc = fmaf(_t_, (h), acc); }

// 1024 threads = 16 waves (4/SIMD). Wave roles (wave w sits on SIMD w%4):
//   waves 0-11 : gate quarters, q = tid/192 -> each SIMD gets 3 gate waves
//   waves 12-15: head partials, one per SIMD
//   phase B    : wave0 = layer-1 combine, wave1 = layer-0 combine,
//                wave2 = head finish (SIMDs 0/1/2)
__global__ __launch_bounds__(1024, 4)
void gru_fused(const float* __restrict__ x,      // [B,T,1]
               const float* __restrict__ h0in,   // [2,B,H]
               const float* __restrict__ W_ih0,  // [192,1]
               const float* __restrict__ W_hh0,  // [192,64]
               const float* __restrict__ b_ih0,  // [192]
               const float* __restrict__ b_hh0,  // [192]
               const float* __restrict__ W_ih1,  // [192,64]
               const float* __restrict__ W_hh1,  // [192,64]
               const float* __restrict__ b_ih1,  // [192]
               const float* __restrict__ b_hh1,  // [192]
               const float* __restrict__ Wh1,    // [64,64]
               const float* __restrict__ bh1,    // [64]
               const float* __restrict__ Wh2,    // [1,64]
               const float* __restrict__ bh2,    // [1]
               float* __restrict__ out)          // y [B*T] ++ hT [2,B,H]
{
    const int b   = blockIdx.x;
    const int tid = threadIdx.x;

    __shared__ __align__(16) float h0_lds[HH];
    __shared__ __align__(16) float h1_lds[HH];
    // planar partials: conflict-free b32 writes/reads (R5's float4 layout cost
    // 1.13e8 bank-conflict cycles from strided component reads)
    __shared__ __align__(16) float pg0[4 * 192];  // gh0 partials
    __shared__ __align__(16) float pg1[4 * 192];  // gx1 partials
    __shared__ __align__(16) float pg2[4 * 192];  // gh1 partials
    __shared__ __align__(16) float ph[4 * 64];    // head partials
    __shared__ __align__(16) float x_lds[TT];

    // ---- preload x row (coalesced float4), init h ----
    {
        const float4* xs = reinterpret_cast<const float4*>(x + (size_t)b * TT);
        float4*       xd = reinterpret_cast<float4*>(x_lds);
        if (tid < TT / 4) xd[tid] = xs[tid];
    }
    if (tid < HH) {
        h0_lds[tid] = h0in[          b * HH + tid];
        h1_lds[tid] = h0in[BB * HH + b * HH + tid];
    }

    // ---- role decode ----
    const bool is_gate = tid < 768;
    int q, t;  // gate: quarter 0-3 / row 0-191. head: quarter 0-3 / row 0-63.
    if (is_gate) { q = tid / 192; t = tid - q * 192; }
    else         { q = (tid - 768) >> 6; t = (tid - 768) & 63; }

    // ---- per-thread weight slices -> AGPRs (16 floats per matrix) ----
    float wA0x,wA0y,wA0z,wA0w, wA1x,wA1y,wA1z,wA1w,
          wA2x,wA2y,wA2z,wA2w, wA3x,wA3y,wA3z,wA3w;
    float wB0x,wB0y,wB0z,wB0w, wB1x,wB1y,wB1z,wB1w,
          wB2x,wB2y,wB2z,wB2w, wB3x,wB3y,wB3z,wB3w;
    float wC0x,wC0y,wC0z,wC0w, wC1x,wC1y,wC1z,wC1w,
          wC2x,wC2y,wC2z,wC2w, wC3x,wC3y,wC3z,wC3w;
    float bAa, bBa, bCa;   // gate biases, AGPR-resident too

#define LOADM(P, ptr) { const float4* _p4 = reinterpret_cast<const float4*>(ptr); \
    float4 f4; \
    f4 = _p4[0]; AW(P##0x, f4.x); AW(P##0y, f4.y); AW(P##0z, f4.z); AW(P##0w, f4.w); \
    f4 = _p4[1]; AW(P##1x, f4.x); AW(P##1y, f4.y); AW(P##1z, f4.z); AW(P##1w, f4.w); \
    f4 = _p4[2]; AW(P##2x, f4.x); AW(P##2y, f4.y); AW(P##2z, f4.z); AW(P##2w, f4.w); \
    f4 = _p4[3]; AW(P##3x, f4.x); AW(P##3y, f4.y); AW(P##3z, f4.z); AW(P##3w, f4.w); }

    if (is_gate) {
        LOADM(wA, W_hh0 + t * HH + q * 16);
        LOADM(wB, W_ih1 + t * HH + q * 16);
        LOADM(wC, W_hh1 + t * HH + q * 16);
        float v0 = (q == 0) ? b_hh0[t] : 0.f;
        float v1 = (q == 0) ? b_ih1[t] : 0.f;
        float v2 = (q == 0) ? b_hh1[t] : 0.f;
        AW(bAa, v0); AW(bBa, v1); AW(bCa, v2);
    } else {
        LOADM(wA, Wh1 + t * HH + q * 16);
    }

    // layer-0 combine consts (wave 1)
    float wih0_r = 0.f, wih0_z = 0.f, wih0_n = 0.f;
    float bih0_r = 0.f, bih0_z = 0.f, bih0_n = 0.f;
    if (tid >= 64 && tid < 128) {
        const int j = tid - 64;
        wih0_r = W_ih0[j];       bih0_r = b_ih0[j];
        wih0_z = W_ih0[j + 64];  bih0_z = b_ih0[j + 64];
        wih0_n = W_ih0[j + 128]; bih0_n = b_ih0[j + 128];
    }
    // head finish consts (wave 2)
    float wh2r = 0.f, bh1r = 0.f, bh2s = 0.f;
    if (tid >= 128 && tid < 192) {
        const int j = tid - 128;
        wh2r = Wh2[j]; bh1r = bh1[j]; bh2s = bh2[0];
    }

    __syncthreads();

    const float4* h0q = reinterpret_cast<const float4*>(h0_lds) + (q << 2);
    const float4* h1q = reinterpret_cast<const float4*>(h1_lds) + (q << 2);

    // gate step for float4-chunk j: 12 MACs, weights read from AGPR
#define GQ(j) { float4 u = h0q[j]; float4 v = h1q[j]; \
    AMAC(a0, wA##j##x, u.x); AMAC(a1, wB##j##x, u.x); AMAC(a2, wC##j##x, v.x); \
    AMAC(a0, wA##j##y, u.y); AMAC(a1, wB##j##y, u.y); AMAC(a2, wC##j##y, v.y); \
    AMAC(a0, wA##j##z, u.z); AMAC(a1, wB##j##z, u.z); AMAC(a2, wC##j##z, v.z); \
    AMAC(a0, wA##j##w, u.w); AMAC(a1, wB##j##w, u.w); AMAC(a2, wC##j##w, v.w); }
#define HQ(j) { float4 v = h1q[j]; \
    AMAC(s, wA##j##x, v.x); AMAC(s, wA##j##y, v.y); \
    AMAC(s, wA##j##z, v.z); AMAC(s, wA##j##w, v.w); }

    // Pipeline, 2 barriers/iter (schedule identical to rounds 1-5):
    //   A(i): partial gh0(i)=W_hh0@h0^i ; gx1(i-1)=W_ih1@h0^i ;
    //         gh1(i-1)=W_hh1@h1^(i-1) ; head partial from h1^(i-1)
    //   B(i): combine layer-1 -> h1^i ; combine layer-0 -> h0^(i+1) ; y[i-2]
    for (int i = 0; i <= TT + 1; ++i) {
        // ---------------- Phase A: quarter-partial dots ----------------
        if (is_gate) {
            float a0, a1, a2;
            AR(a0, bAa); AR(a1, bBa); AR(a2, bCa);
            GQ(0) GQ(1) GQ(2) GQ(3)
            pg0[q * 192 + t] = a0;   // conflict-free stride-4B writes
            pg1[q * 192 + t] = a1;
            pg2[q * 192 + t] = a2;
        } else {
            float s = 0.f;
            HQ(0) HQ(1) HQ(2) HQ(3)
            ph[q * 64 + t] = s;
        }
        __syncthreads();

        // ---------------- Phase B: combines ----------------
        if (tid < 64) {
            // layer-1 combine for step (i-1)
            const int j = tid;
            float sxr = 0.f, shr = 0.f, sxz = 0.f, shz = 0.f, sxn = 0.f, shn = 0.f;
            #pragma unroll
            for (int qq = 0; qq < 4; ++qq) {
                sxr += pg1[qq * 192 + j];       shr += pg2[qq * 192 + j];
                sxz += pg1[qq * 192 + j + 64];  shz += pg2[qq * 192 + j + 64];
                sxn += pg1[qq * 192 + j + 128]; shn += pg2[qq * 192 + j + 128];
            }
            float r = sigmoid_f(sxr + shr);
            float z = sigmoid_f(sxz + shz);
            float n = tanh_f(fmaf(r, shn, sxn));
            if (i >= 1 && i <= TT) {
                float hp = h1_lds[j];
                h1_lds[j] = fmaf(z, hp - n, n);   // (1-z)*n + z*h
            }
        } else if (tid < 128) {
            // layer-0 combine for step i
            const int j  = tid - 64;
            const int xi = (i < TT) ? i : (TT - 1);
            float g0 = 0.f, g1 = 0.f, g2 = 0.f;
            #pragma unroll
            for (int qq = 0; qq < 4; ++qq) {
                g0 += pg0[qq * 192 + j];
                g1 += pg0[qq * 192 + j + 64];
                g2 += pg0[qq * 192 + j + 128];
            }
            float xv = x_lds[xi];
            float r = sigmoid_f(fmaf(xv, wih0_r, bih0_r) + g0);
            float z = sigmoid_f(fmaf(xv, wih0_z, bih0_z) + g1);
            float n = tanh_f(fmaf(r, g2, fmaf(xv, wih0_n, bih0_n)));
            if (i < TT) {
                float hp = h0_lds[j];
                h0_lds[j] = fmaf(z, hp - n, n);
            }
        } else if (tid < 192) {
            // head finish for y[i-2]
            const int j = tid - 128;
            float s = ph[j] + ph[64 + j] + ph[128 + j] + ph[192 + j] + bh1r;
            float p = fmaxf(s, 0.f) * wh2r;
            #pragma unroll
            for (int m = 1; m < 64; m <<= 1) p += __shfl_xor(p, m, 64);
            if (tid == 128 && i >= 2) out[(size_t)b * TT + (i - 2)] = p + bh2s;
        }
        __syncthreads();
    }

    // final hidden states: hT[2,B,H]
    if (tid < HH) {
        out[YSZ +           b * HH + tid] = h0_lds[tid];
        out[YSZ + BB * HH + b * HH + tid] = h1_lds[tid];
    }
}

extern "C" void kernel_launch(void* const* d_in, const int* in_sizes, int n_in,
                              void* d_out, int out_size, void* d_ws, size_t ws_size,
                              hipStream_t stream) {
    const float* x     = (const float*)d_in[0];
    const float* h0in  = (const float*)d_in[1];
    const float* W_ih0 = (const float*)d_in[2];
    const float* W_hh0 = (const float*)d_in[3];
    const float* b_ih0 = (const float*)d_in[4];
    const float* b_hh0 = (const float*)d_in[5];
    const float* W_ih1 = (const float*)d_in[6];
    const float* W_hh1 = (const float*)d_in[7];
    const float* b_ih1 = (const float*)d_in[8];
    const float* b_hh1 = (const float*)d_in[9];
    const float* Wh1   = (const float*)d_in[10];
    const float* bh1   = (const float*)d_in[11];
    const float* Wh2   = (const float*)d_in[12];
    const float* bh2   = (const float*)d_in[13];
    float* out = (float*)d_out;

    gru_fused<<<dim3(BB), dim3(1024), 0, stream>>>(
        x, h0in, W_ih0, W_hh0, b_ih0, b_hh0,
        W_ih1, W_hh1, b_ih1, b_hh1, Wh1, bh1, Wh2, bh2, out);
}